// Round 1
// baseline (1896.947 us; speedup 1.0000x reference)
//
#include <hip/hip_runtime.h>
#include <hip/hip_bf16.h>

#define NB 2
#define NS 4096
#define NE 512
#define NH 8
#define ND 64
#define NHD 512

typedef __attribute__((ext_vector_type(8))) short short8;
typedef __attribute__((ext_vector_type(4))) float floatx4;

#define MFMA16(a, b, c) __builtin_amdgcn_mfma_f32_16x16x32_bf16((a), (b), (c), 0, 0, 0)

union Cvt8 { uint4 u; short8 s; };
static __device__ __forceinline__ short8 ld8(const __hip_bfloat16* p) {
  Cvt8 c; c.u = *(const uint4*)p; return c.s;
}
union BH { __hip_bfloat16 h; short s; };
static __device__ __forceinline__ short f2bs(float x) {
  BH u; u.h = __float2bfloat16(x); return u.s;
}

// ---------------------------------------------------------------------------
// Kernel 0: pack int32 mask (B,H,S,S) -> 1 bit per element, as uint64 words.
// word W covers mask ints [W*64, W*64+64); bit l of word W = (mask[W*64+l]!=0).
// Pure BW kernel: reads 1.07 GB once; flash then reads 33.5 MB instead.
// 2048 blocks x 256 thr = 8192 waves; 512 words/wave, contiguous, unroll 4.
// ---------------------------------------------------------------------------
__global__ __launch_bounds__(256) void mask_pack(const int* __restrict__ mask,
                                                 unsigned long long* __restrict__ bits) {
  const int lane = threadIdx.x & 63;
  const long wid = (long)((blockIdx.x * 256 + threadIdx.x) >> 6);  // 0..8191
  const long base = wid * 512;                                     // first word
  const int* p = mask + base * 64 + lane;
  for (int i = 0; i < 512; i += 4) {
    const int m0 = p[(long)(i + 0) * 64];
    const int m1 = p[(long)(i + 1) * 64];
    const int m2 = p[(long)(i + 2) * 64];
    const int m3 = p[(long)(i + 3) * 64];
    const unsigned long long b0 = __ballot(m0 != 0);
    const unsigned long long b1 = __ballot(m1 != 0);
    const unsigned long long b2 = __ballot(m2 != 0);
    const unsigned long long b3 = __ballot(m3 != 0);
    if (lane == 0) {
      *(ulonglong2*)(bits + base + i) = ulonglong2{b0, b1};
      *(ulonglong2*)(bits + base + i + 2) = ulonglong2{b2, b3};
    }
  }
}

// ---------------------------------------------------------------------------
// Kernel 1: convert f32 -> bf16 and transpose 512x512 weights (W[k][n] -> Wt[n][k])
// ---------------------------------------------------------------------------
__global__ __launch_bounds__(256) void wconv(
    const float* w0, const float* w1, const float* w2, const float* w3,
    __hip_bfloat16* t0, __hip_bfloat16* t1,
    __hip_bfloat16* t2, __hip_bfloat16* t3) {
  __shared__ __hip_bfloat16 tile[64][72];
  const float* src;
  __hip_bfloat16* dst;
  switch (blockIdx.z) {
    case 0: src = w0; dst = t0; break;
    case 1: src = w1; dst = t1; break;
    case 2: src = w2; dst = t2; break;
    default: src = w3; dst = t3; break;
  }
  const int tx = threadIdx.x & 63, ty = threadIdx.x >> 6;
  const int n0 = blockIdx.x * 64, k0 = blockIdx.y * 64;
  for (int r = ty; r < 64; r += 4)
    tile[r][tx] = __float2bfloat16(src[(long)(k0 + r) * 512 + n0 + tx]);
  __syncthreads();
  for (int r = ty; r < 64; r += 4)
    dst[(long)(n0 + r) * 512 + k0 + tx] = tile[tx][r];
}

// ---------------------------------------------------------------------------
// Kernel 2: QKV projection GEMM.  A (f32, M x 512) @ W^T (bf16, 512 x 512)
// -> q/k/v in (B,H,S,D) bf16.  grid (M/64, 8, 3); 4 waves/block.
// Q output (z==0) pre-scaled by 1/sqrt(D)=0.125 (exact power of 2, so the
// bf16 rounding is bit-identical to scaling the scores later).
// ---------------------------------------------------------------------------
__global__ __launch_bounds__(256) void gemm_qkv(
    const float* A0, const float* A1, const float* A2,
    const __hip_bfloat16* W0, const __hip_bfloat16* W1, const __hip_bfloat16* W2,
    __hip_bfloat16* O0, __hip_bfloat16* O1, __hip_bfloat16* O2) {
  const float* A;
  const __hip_bfloat16* Wt;
  __hip_bfloat16* O;
  switch (blockIdx.z) {
    case 0: A = A0; Wt = W0; O = O0; break;
    case 1: A = A1; Wt = W1; O = O1; break;
    default: A = A2; Wt = W2; O = O2; break;
  }
  const int lane = threadIdx.x & 63;
  const int w = threadIdx.x >> 6;
  const int c = lane & 15, g = lane >> 4;
  const int m0 = blockIdx.x * 64 + w * 16;
  const int n0 = blockIdx.y * 64;

  floatx4 acc[4] = {};
  const float* ap = A + (long)(m0 + c) * 512 + g * 8;
  const __hip_bfloat16* wp = Wt + (long)(n0 + c) * 512 + g * 8;
  for (int ks = 0; ks < 512; ks += 32) {
    const float4 f0 = *(const float4*)(ap + ks);
    const float4 f1 = *(const float4*)(ap + ks + 4);
    short8 a;
    a[0] = f2bs(f0.x); a[1] = f2bs(f0.y); a[2] = f2bs(f0.z); a[3] = f2bs(f0.w);
    a[4] = f2bs(f1.x); a[5] = f2bs(f1.y); a[6] = f2bs(f1.z); a[7] = f2bs(f1.w);
#pragma unroll
    for (int t = 0; t < 4; ++t) {
      short8 b = ld8(wp + t * 16 * 512 + ks);
      acc[t] = MFMA16(a, b, acc[t]);
    }
  }
  const float sc = (blockIdx.z == 0) ? 0.125f : 1.0f;
#pragma unroll
  for (int t = 0; t < 4; ++t) {
#pragma unroll
    for (int r = 0; r < 4; ++r) {
      const int m = m0 + g * 4 + r;
      const int n = n0 + t * 16 + c;
      const int bb = m >> 12, s = m & 4095, h = n >> 6, d = n & 63;
      O[(((long)bb * NH + h) * NS + s) * ND + d] = __float2bfloat16(acc[t][r] * sc);
    }
  }
}

// ---------------------------------------------------------------------------
// Kernel 3: fused flash attention; mask consumed as packed bits (uint64/row/tile).
// grid (S/64, H, B); block 256 = 4 waves; wave handles 16 q-rows.
// Two barriers/tile: staging->compute, and compute->next-staging.  The P
// LDS round-trip is wave-private (Pw), so program order + compiler lgkmcnt
// suffice (per-lane MayAlias on Pb forces ordering).
// ---------------------------------------------------------------------------
#define VPAD 72
__device__ __forceinline__ int vswz(int row) { return ((row >> 3) & 7) * 8; }

__global__ __launch_bounds__(256) void flash_attn(
    const __hip_bfloat16* Q, const __hip_bfloat16* K, const __hip_bfloat16* V,
    const unsigned long long* __restrict__ Mb, __hip_bfloat16* AO) {
  __shared__ __hip_bfloat16 Ks[64 * VPAD];
  __shared__ __hip_bfloat16 Vt[64 * VPAD];
  __shared__ __hip_bfloat16 Pb[4 * 16 * VPAD];

  const int tid = threadIdx.x;
  const int lane = tid & 63, w = tid >> 6;
  const int c = lane & 15, g = lane >> 4;
  const int bz = blockIdx.z, hy = blockIdx.y;
  const int q0 = blockIdx.x * 64 + w * 16;
  const long headbase = ((long)bz * NH + hy) * NS;
  // mask words for this wave's 16 q-rows: row (q0+g*4+r), word index kt.
  const unsigned long long* mrp0 = Mb + ((headbase + q0 + g * 4) << 6);

  const short8 qf0 = ld8(Q + (headbase + q0 + c) * ND + g * 8);
  const short8 qf1 = ld8(Q + (headbase + q0 + c) * ND + 32 + g * 8);

  floatx4 oacc[4] = {};
  float m_i[4], l_i[4];
#pragma unroll
  for (int r = 0; r < 4; ++r) { m_i[r] = -1e30f; l_i[r] = 0.f; }
  __hip_bfloat16* Pw = Pb + w * 16 * VPAD;

  for (int kt = 0; kt < 64; ++kt) {
    const int k0 = kt * 64;
#pragma unroll
    for (int it = 0; it < 2; ++it) {
      const int chunk = tid + it * 256;
      const int kc = chunk >> 3;
      const int dd = (chunk & 7) * 8;
      const long gbase = (headbase + k0 + kc) * ND + dd;
      *(uint4*)&Ks[kc * VPAD + dd] = *(const uint4*)(K + gbase);
      uint4 vv = *(const uint4*)(V + gbase);
      const __hip_bfloat16* ve = (const __hip_bfloat16*)&vv;
#pragma unroll
      for (int j = 0; j < 8; ++j) {
        const int row = dd + j;
        Vt[row * VPAD + (kc ^ vswz(row))] = ve[j];
      }
    }
    __syncthreads();

    // hoisted mask-word loads (4 x 8B; latency hides under QK^T MFMAs)
    unsigned long long mrow[4];
    mrow[0] = mrp0[kt];
    mrow[1] = mrp0[64 + kt];
    mrow[2] = mrp0[128 + kt];
    mrow[3] = mrp0[192 + kt];

    // ---- S = Q K^T ----  (Q already scaled by 1/sqrt(D))
    floatx4 sacc[4] = {};
#pragma unroll
    for (int t = 0; t < 4; ++t) {
      short8 b0 = ld8(&Ks[(t * 16 + c) * VPAD + g * 8]);
      sacc[t] = MFMA16(qf0, b0, sacc[t]);
      short8 b1 = ld8(&Ks[(t * 16 + c) * VPAD + 32 + g * 8]);
      sacc[t] = MFMA16(qf1, b1, sacc[t]);
    }

    // ---- mask (bit test) + row max ----
    float mx[4];
#pragma unroll
    for (int r = 0; r < 4; ++r) {
      const unsigned long long ms = mrow[r] >> c;  // bits 0/16/32/48 = t 0..3
      float s0 = ((unsigned)ms & 1u) ? -1e10f : sacc[0][r];
      float s1 = ((unsigned)(ms >> 16) & 1u) ? -1e10f : sacc[1][r];
      float s2 = ((unsigned)(ms >> 32) & 1u) ? -1e10f : sacc[2][r];
      float s3 = ((unsigned)(ms >> 48) & 1u) ? -1e10f : sacc[3][r];
      sacc[0][r] = s0; sacc[1][r] = s1; sacc[2][r] = s2; sacc[3][r] = s3;
      float mxr = fmaxf(fmaxf(s0, s1), fmaxf(s2, s3));
#pragma unroll
      for (int off = 1; off < 16; off <<= 1)
        mxr = fmaxf(mxr, __shfl_xor(mxr, off));
      mx[r] = mxr;
    }

    // ---- online softmax with defer-rescale (skip alpha path when no row's
    // max grew anywhere in the wave; wave-uniform branch via ballot) ----
    const bool grow = (mx[0] > m_i[0]) | (mx[1] > m_i[1]) |
                      (mx[2] > m_i[2]) | (mx[3] > m_i[3]);
    if (__ballot(grow) != 0ull) {
      float alpha[4];
#pragma unroll
      for (int r = 0; r < 4; ++r) {
        const float mn = fmaxf(m_i[r], mx[r]);
        const float al = __expf(m_i[r] - mn);
        float ps = 0.f;
#pragma unroll
        for (int t = 0; t < 4; ++t) {
          const float p = __expf(sacc[t][r] - mn);
          sacc[t][r] = p;
          ps += p;
        }
#pragma unroll
        for (int off = 1; off < 16; off <<= 1)
          ps += __shfl_xor(ps, off);
        m_i[r] = mn;
        l_i[r] = l_i[r] * al + ps;
        alpha[r] = al;
      }
#pragma unroll
      for (int t = 0; t < 4; ++t)
#pragma unroll
        for (int r = 0; r < 4; ++r) oacc[t][r] *= alpha[r];
    } else {
#pragma unroll
      for (int r = 0; r < 4; ++r) {
        float ps = 0.f;
#pragma unroll
        for (int t = 0; t < 4; ++t) {
          const float p = __expf(sacc[t][r] - m_i[r]);  // <= 1, no growth
          sacc[t][r] = p;
          ps += p;
        }
#pragma unroll
        for (int off = 1; off < 16; off <<= 1)
          ps += __shfl_xor(ps, off);
        l_i[r] += ps;
      }
    }

    // ---- P -> wave-private LDS (no cross-wave barrier needed) ----
#pragma unroll
    for (int r = 0; r < 4; ++r)
#pragma unroll
      for (int t = 0; t < 4; ++t)
        Pw[(g * 4 + r) * VPAD + t * 16 + c] = __float2bfloat16(sacc[t][r]);

    // ---- O += P @ V ----
#pragma unroll
    for (int ks2 = 0; ks2 < 2; ++ks2) {
      short8 af = ld8(&Pw[c * VPAD + ks2 * 32 + g * 8]);
#pragma unroll
      for (int t = 0; t < 4; ++t) {
        const int row = t * 16 + c;
        short8 bf = ld8(&Vt[row * VPAD + ((ks2 * 32 + g * 8) ^ vswz(row))]);
        oacc[t] = MFMA16(af, bf, oacc[t]);
      }
    }
    __syncthreads();
  }

#pragma unroll
  for (int t = 0; t < 4; ++t) {
#pragma unroll
    for (int r = 0; r < 4; ++r) {
      const int qrow = q0 + g * 4 + r;
      const float v = oacc[t][r] / l_i[r];
      AO[((long)bz * NS + qrow) * NHD + hy * 64 + t * 16 + c] = __float2bfloat16(v);
    }
  }
}

// ---------------------------------------------------------------------------
// Kernel 4: output projection.  A (bf16, M x 512) @ Wo^T -> out (f32).
// ---------------------------------------------------------------------------
__global__ __launch_bounds__(256) void gemm_out(
    const __hip_bfloat16* A, const __hip_bfloat16* Wt, float* O) {
  const int lane = threadIdx.x & 63;
  const int w = threadIdx.x >> 6;
  const int c = lane & 15, g = lane >> 4;
  const int m0 = blockIdx.x * 64 + w * 16;
  const int n0 = blockIdx.y * 64;

  floatx4 acc[4] = {};
  const __hip_bfloat16* ap = A + (long)(m0 + c) * 512 + g * 8;
  const __hip_bfloat16* wp = Wt + (long)(n0 + c) * 512 + g * 8;
  for (int ks = 0; ks < 512; ks += 32) {
    short8 a = ld8(ap + ks);
#pragma unroll
    for (int t = 0; t < 4; ++t) {
      short8 b = ld8(wp + t * 16 * 512 + ks);
      acc[t] = MFMA16(a, b, acc[t]);
    }
  }
#pragma unroll
  for (int t = 0; t < 4; ++t)
#pragma unroll
    for (int r = 0; r < 4; ++r)
      O[(long)(m0 + g * 4 + r) * 512 + n0 + t * 16 + c] = acc[t][r];
}

// ---------------------------------------------------------------------------
extern "C" void kernel_launch(void* const* d_in, const int* in_sizes, int n_in,
                              void* d_out, int out_size, void* d_ws, size_t ws_size,
                              hipStream_t stream) {
  const float* q_in = (const float*)d_in[0];
  const float* k_in = (const float*)d_in[1];
  const float* v_in = (const float*)d_in[2];
  const int* mask = (const int*)d_in[3];
  const float* Wq = (const float*)d_in[4];
  const float* Wk = (const float*)d_in[5];
  const float* Wv = (const float*)d_in[6];
  const float* Wo = (const float*)d_in[7];
  float* out = (float*)d_out;

  char* base = (char*)d_ws;
  const size_t MB = 1u << 20;
  __hip_bfloat16* wtq = (__hip_bfloat16*)(base);
  __hip_bfloat16* wtk = (__hip_bfloat16*)(base + 512 * 1024);
  __hip_bfloat16* wtv = (__hip_bfloat16*)(base + 1 * MB);
  __hip_bfloat16* wto = (__hip_bfloat16*)(base + 1 * MB + 512 * 1024);
  __hip_bfloat16* qp = (__hip_bfloat16*)(base + 2 * MB);    // 8 MB each
  __hip_bfloat16* kp = (__hip_bfloat16*)(base + 10 * MB);
  __hip_bfloat16* vp = (__hip_bfloat16*)(base + 18 * MB);
  __hip_bfloat16* ao = (__hip_bfloat16*)(base + 26 * MB);
  unsigned long long* mb = (unsigned long long*)(base + 34 * MB);  // 33.6 MB (ws is ~4 GB per harness fills)

  mask_pack<<<dim3(2048), 256, 0, stream>>>(mask, mb);
  wconv<<<dim3(8, 8, 4), 256, 0, stream>>>(Wq, Wk, Wv, Wo, wtq, wtk, wtv, wto);
  gemm_qkv<<<dim3(128, 8, 3), 256, 0, stream>>>(
      q_in, k_in, v_in, wtq, wtk, wtv, qp, kp, vp);
  flash_attn<<<dim3(NS / 64, NH, NB), 256, 0, stream>>>(qp, kp, vp, mb, ao);
  gemm_out<<<dim3(128, 8), 256, 0, stream>>>(ao, wto, out);
}

// Round 3
// 1752.163 us; speedup vs baseline: 1.0826x; 1.0826x over previous
//
#include <hip/hip_runtime.h>
#include <hip/hip_bf16.h>

#define NB 2
#define NS 4096
#define NE 512
#define NH 8
#define ND 64
#define NHD 512

typedef __attribute__((ext_vector_type(8))) short short8;
typedef __attribute__((ext_vector_type(4))) float floatx4;
typedef __attribute__((ext_vector_type(16))) float f32x16;

#define MFMA16(a, b, c) __builtin_amdgcn_mfma_f32_16x16x32_bf16((a), (b), (c), 0, 0, 0)
#define MFMA32(a, b, c) __builtin_amdgcn_mfma_f32_32x32x16_bf16((a), (b), (c), 0, 0, 0)

union Cvt8 { uint4 u; short8 s; };
static __device__ __forceinline__ short8 ld8(const __hip_bfloat16* p) {
  Cvt8 c; c.u = *(const uint4*)p; return c.s;
}
union BH { __hip_bfloat16 h; short s; };
static __device__ __forceinline__ short f2bs(float x) {
  BH u; u.h = __float2bfloat16(x); return u.s;
}
// pack two f32 -> one u32 of 2x bf16 (lo = a, hi = b); RNE, matches __float2bfloat16
static __device__ __forceinline__ unsigned pk2(float a, float b) {
  unsigned d;
  asm("v_cvt_pk_bf16_f32 %0, %1, %2" : "=v"(d) : "v"(a), "v"(b));
  return d;
}

// ---------------------------------------------------------------------------
// Kernel 0: pack int32 mask (B,H,S,S) -> 1 bit per element, as uint64 words.
// ---------------------------------------------------------------------------
__global__ __launch_bounds__(256) void mask_pack(const int* __restrict__ mask,
                                                 unsigned long long* __restrict__ bits) {
  const int lane = threadIdx.x & 63;
  const long wid = (long)((blockIdx.x * 256 + threadIdx.x) >> 6);  // 0..8191
  const long base = wid * 512;                                     // first word
  const int* p = mask + base * 64 + lane;
  for (int i = 0; i < 512; i += 4) {
    const int m0 = p[(long)(i + 0) * 64];
    const int m1 = p[(long)(i + 1) * 64];
    const int m2 = p[(long)(i + 2) * 64];
    const int m3 = p[(long)(i + 3) * 64];
    const unsigned long long b0 = __ballot(m0 != 0);
    const unsigned long long b1 = __ballot(m1 != 0);
    const unsigned long long b2 = __ballot(m2 != 0);
    const unsigned long long b3 = __ballot(m3 != 0);
    if (lane == 0) {
      *(ulonglong2*)(bits + base + i) = ulonglong2{b0, b1};
      *(ulonglong2*)(bits + base + i + 2) = ulonglong2{b2, b3};
    }
  }
}

// ---------------------------------------------------------------------------
// Kernel 1: convert f32 -> bf16 and transpose 512x512 weights
// ---------------------------------------------------------------------------
__global__ __launch_bounds__(256) void wconv(
    const float* w0, const float* w1, const float* w2, const float* w3,
    __hip_bfloat16* t0, __hip_bfloat16* t1,
    __hip_bfloat16* t2, __hip_bfloat16* t3) {
  __shared__ __hip_bfloat16 tile[64][72];
  const float* src;
  __hip_bfloat16* dst;
  switch (blockIdx.z) {
    case 0: src = w0; dst = t0; break;
    case 1: src = w1; dst = t1; break;
    case 2: src = w2; dst = t2; break;
    default: src = w3; dst = t3; break;
  }
  const int tx = threadIdx.x & 63, ty = threadIdx.x >> 6;
  const int n0 = blockIdx.x * 64, k0 = blockIdx.y * 64;
  for (int r = ty; r < 64; r += 4)
    tile[r][tx] = __float2bfloat16(src[(long)(k0 + r) * 512 + n0 + tx]);
  __syncthreads();
  for (int r = ty; r < 64; r += 4)
    dst[(long)(n0 + r) * 512 + k0 + tx] = tile[tx][r];
}

// ---------------------------------------------------------------------------
// Kernel 2: QKV projection GEMM; Q output pre-scaled by 1/sqrt(D)=0.125
// ---------------------------------------------------------------------------
__global__ __launch_bounds__(256) void gemm_qkv(
    const float* A0, const float* A1, const float* A2,
    const __hip_bfloat16* W0, const __hip_bfloat16* W1, const __hip_bfloat16* W2,
    __hip_bfloat16* O0, __hip_bfloat16* O1, __hip_bfloat16* O2) {
  const float* A;
  const __hip_bfloat16* Wt;
  __hip_bfloat16* O;
  switch (blockIdx.z) {
    case 0: A = A0; Wt = W0; O = O0; break;
    case 1: A = A1; Wt = W1; O = O1; break;
    default: A = A2; Wt = W2; O = O2; break;
  }
  const int lane = threadIdx.x & 63;
  const int w = threadIdx.x >> 6;
  const int c = lane & 15, g = lane >> 4;
  const int m0 = blockIdx.x * 64 + w * 16;
  const int n0 = blockIdx.y * 64;

  floatx4 acc[4] = {};
  const float* ap = A + (long)(m0 + c) * 512 + g * 8;
  const __hip_bfloat16* wp = Wt + (long)(n0 + c) * 512 + g * 8;
  for (int ks = 0; ks < 512; ks += 32) {
    const float4 f0 = *(const float4*)(ap + ks);
    const float4 f1 = *(const float4*)(ap + ks + 4);
    short8 a;
    a[0] = f2bs(f0.x); a[1] = f2bs(f0.y); a[2] = f2bs(f0.z); a[3] = f2bs(f0.w);
    a[4] = f2bs(f1.x); a[5] = f2bs(f1.y); a[6] = f2bs(f1.z); a[7] = f2bs(f1.w);
#pragma unroll
    for (int t = 0; t < 4; ++t) {
      short8 b = ld8(wp + t * 16 * 512 + ks);
      acc[t] = MFMA16(a, b, acc[t]);
    }
  }
  const float sc = (blockIdx.z == 0) ? 0.125f : 1.0f;
#pragma unroll
  for (int t = 0; t < 4; ++t) {
#pragma unroll
    for (int r = 0; r < 4; ++r) {
      const int m = m0 + g * 4 + r;
      const int n = n0 + t * 16 + c;
      const int bb = m >> 12, s = m & 4095, h = n >> 6, d = n & 63;
      O[(((long)bb * NH + h) * NS + s) * ND + d] = __float2bfloat16(acc[t][r] * sc);
    }
  }
}

// ---------------------------------------------------------------------------
// Kernel 3: fused flash attention, swapped-QK^T 32x32 structure.
// grid (S/128, H, B); block 256 = 4 waves; each wave owns 32 q-rows.
// mfma(K,Q) -> lane (ql,hl) holds S[k=(r&3)+8*(r>>2)+4*hl (+32 for s1)][q=ql].
// Softmax fully in-register; cross-half combines and the P->A-frag
// redistribution use __shfl_xor(,32) (well-defined semantics) + selects.
// A/B fragments both use positional (contiguous) k-labeling, so correctness
// is independent of the HW's internal k-permutation.
// ---------------------------------------------------------------------------
#define VPAD 72
__device__ __forceinline__ int vswz(int row) { return ((row >> 3) & 7) * 8; }

__global__ __launch_bounds__(256) void flash_attn(
    const __hip_bfloat16* Q, const __hip_bfloat16* K, const __hip_bfloat16* V,
    const unsigned long long* __restrict__ Mb, __hip_bfloat16* AO) {
  __shared__ __hip_bfloat16 Ks[64 * VPAD];
  __shared__ __hip_bfloat16 Vt[64 * VPAD];

  const int tid = threadIdx.x;
  const int lane = tid & 63, w = tid >> 6;
  const int ql = lane & 31, hl = lane >> 5;
  const int bz = blockIdx.z, hy = blockIdx.y;
  const int q0 = blockIdx.x * 128 + w * 32;
  const long headbase = ((long)bz * NH + hy) * NS;

  // Q fragments (B-operand): lane holds Q[q0+ql][ds*16 + hl*8 + j]
  short8 qf[4];
#pragma unroll
  for (int ds = 0; ds < 4; ++ds)
    qf[ds] = ld8(Q + (headbase + q0 + ql) * ND + ds * 16 + hl * 8);

  f32x16 oacc0 = {}, oacc1 = {};
  float m_i = -1e30f, l_i = 0.f;
  const unsigned long long* mrp = Mb + ((headbase + q0 + ql) << 6);

  for (int kt = 0; kt < 64; ++kt) {
    const int k0 = kt * 64;
#pragma unroll
    for (int it = 0; it < 2; ++it) {
      const int chunk = tid + it * 256;
      const int kc = chunk >> 3;
      const int dd = (chunk & 7) * 8;
      const long gbase = (headbase + k0 + kc) * ND + dd;
      *(uint4*)&Ks[kc * VPAD + dd] = *(const uint4*)(K + gbase);
      uint4 vv = *(const uint4*)(V + gbase);
      const __hip_bfloat16* ve = (const __hip_bfloat16*)&vv;
#pragma unroll
      for (int j = 0; j < 8; ++j) {
        const int row = dd + j;
        Vt[row * VPAD + (kc ^ vswz(row))] = ve[j];
      }
    }
    const unsigned long long mword = mrp[kt];  // issued pre-barrier, hides
    __syncthreads();

    // ---- S = K Q^T (swapped) ----
    f32x16 s0 = {}, s1 = {};
#pragma unroll
    for (int ds = 0; ds < 4; ++ds) {
      short8 a0 = ld8(&Ks[ql * VPAD + ds * 16 + hl * 8]);
      s0 = MFMA32(a0, qf[ds], s0);
      short8 a1 = ld8(&Ks[(32 + ql) * VPAD + ds * 16 + hl * 8]);
      s1 = MFMA32(a1, qf[ds], s1);
    }

    // ---- mask (bit test on own q-row word) + in-lane row max ----
    // k for s0[r] = kt*64 + (r&3) + 8*(r>>2) + 4*hl; s1: +32
    const unsigned long long wsh = mword >> (hl * 4);
    const unsigned mlo = (unsigned)wsh;
    const unsigned mhi = (unsigned)(wsh >> 32);
    float mt = -1e30f;
#pragma unroll
    for (int r = 0; r < 16; ++r) {
      const int idx = (r & 3) + 8 * (r >> 2);
      const float a0 = ((mlo >> idx) & 1u) ? -1e10f : s0[r];
      const float a1 = ((mhi >> idx) & 1u) ? -1e10f : s1[r];
      s0[r] = a0; s1[r] = a1;
      mt = fmaxf(mt, fmaxf(a0, a1));
    }
    mt = fmaxf(mt, __shfl_xor(mt, 32));  // combine k-halves (same q)

    // ---- defer-rescale (THR=8): wave-uniform, fires rarely ----
    if (__ballot(mt > m_i + 8.0f) != 0ull) {
      const float mn = fmaxf(m_i, mt);
      const float al = __expf(m_i - mn);
      m_i = mn;
      l_i *= al;
#pragma unroll
      for (int r = 0; r < 16; ++r) {
        const float ab = __shfl(al, (r & 3) + 8 * (r >> 2) + 4 * hl);
        oacc0[r] *= ab;
        oacc1[r] *= ab;
      }
    }

    // ---- exp + in-lane sum ----
    float ss = 0.f;
#pragma unroll
    for (int r = 0; r < 16; ++r) {
      const float p0 = __expf(s0[r] - m_i);
      const float p1 = __expf(s1[r] - m_i);
      s0[r] = p0; s1[r] = p1;
      ss += p0 + p1;
    }
    ss += __shfl_xor(ss, 32);
    l_i += ss;

    // ---- P->bf16 A-frags and O += P @ V ----
    // Group g of 8 values pp[0..7] has k-labels (r&3)+8*(r>>2)+4*hl.
    // Build contiguous-labeled frag words via 2 shfl_xor(32) + selects:
    //   w0..w3 at lane hl hold k = 8*hl + (2w, 2w+1)  [within this 16-group]
#pragma unroll
    for (int ks = 0; ks < 4; ++ks) {
      float pp[8];
#pragma unroll
      for (int j = 0; j < 8; ++j)
        pp[j] = (ks < 2) ? ((ks & 1) ? s0[8 + j] : s0[j])
                         : ((ks & 1) ? s1[8 + j] : s1[j]);
      const unsigned pk01 = pk2(pp[0], pp[1]);  // hl0:(0,1)  hl1:(4,5)
      const unsigned pk23 = pk2(pp[2], pp[3]);  // hl0:(2,3)  hl1:(6,7)
      const unsigned pk45 = pk2(pp[4], pp[5]);  // hl0:(8,9)  hl1:(12,13)
      const unsigned pk67 = pk2(pp[6], pp[7]);  // hl0:(10,11) hl1:(14,15)
      const unsigned send1 = hl ? pk01 : pk45;
      const unsigned send2 = hl ? pk23 : pk67;
      const unsigned recv1 = __shfl_xor(send1, 32);  // hl0:(4,5)  hl1:(8,9)
      const unsigned recv2 = __shfl_xor(send2, 32);  // hl0:(6,7)  hl1:(10,11)
      Cvt8 pc;
      pc.u = make_uint4(hl ? recv1 : pk01,   // w0: hl0 (0,1)  hl1 (8,9)
                        hl ? recv2 : pk23,   // w1: hl0 (2,3)  hl1 (10,11)
                        hl ? pk45 : recv1,   // w2: hl0 (4,5)  hl1 (12,13)
                        hl ? pk67 : recv2);  // w3: hl0 (6,7)  hl1 (14,15)
      const int cb = ks * 16 + hl * 8;
      const short8 v0 = ld8(&Vt[ql * VPAD + (cb ^ vswz(ql))]);
      oacc0 = MFMA32(pc.s, v0, oacc0);
      const short8 v1 = ld8(&Vt[(32 + ql) * VPAD + (cb ^ vswz(32 + ql))]);
      oacc1 = MFMA32(pc.s, v1, oacc1);
    }
    __syncthreads();
  }

  // ---- epilogue: fetch l for own output rows, normalize, store ----
#pragma unroll
  for (int r = 0; r < 16; ++r) {
    const int cr = (r & 3) + 8 * (r >> 2) + 4 * hl;
    const float lb = __shfl(l_i, cr);  // l_i for q=cr lives at lane cr
    const float inv = 1.0f / lb;
    const long obase = ((long)bz * NS + q0 + cr) * NHD + hy * 64;
    AO[obase + ql] = __float2bfloat16(oacc0[r] * inv);
    AO[obase + 32 + ql] = __float2bfloat16(oacc1[r] * inv);
  }
}

// ---------------------------------------------------------------------------
// Kernel 4: output projection.  A (bf16, M x 512) @ Wo^T -> out (f32).
// ---------------------------------------------------------------------------
__global__ __launch_bounds__(256) void gemm_out(
    const __hip_bfloat16* A, const __hip_bfloat16* Wt, float* O) {
  const int lane = threadIdx.x & 63;
  const int w = threadIdx.x >> 6;
  const int c = lane & 15, g = lane >> 4;
  const int m0 = blockIdx.x * 64 + w * 16;
  const int n0 = blockIdx.y * 64;

  floatx4 acc[4] = {};
  const __hip_bfloat16* ap = A + (long)(m0 + c) * 512 + g * 8;
  const __hip_bfloat16* wp = Wt + (long)(n0 + c) * 512 + g * 8;
  for (int ks = 0; ks < 512; ks += 32) {
    short8 a = ld8(ap + ks);
#pragma unroll
    for (int t = 0; t < 4; ++t) {
      short8 b = ld8(wp + t * 16 * 512 + ks);
      acc[t] = MFMA16(a, b, acc[t]);
    }
  }
#pragma unroll
  for (int t = 0; t < 4; ++t)
#pragma unroll
    for (int r = 0; r < 4; ++r)
      O[(long)(m0 + g * 4 + r) * 512 + n0 + t * 16 + c] = acc[t][r];
}

// ---------------------------------------------------------------------------
extern "C" void kernel_launch(void* const* d_in, const int* in_sizes, int n_in,
                              void* d_out, int out_size, void* d_ws, size_t ws_size,
                              hipStream_t stream) {
  const float* q_in = (const float*)d_in[0];
  const float* k_in = (const float*)d_in[1];
  const float* v_in = (const float*)d_in[2];
  const int* mask = (const int*)d_in[3];
  const float* Wq = (const float*)d_in[4];
  const float* Wk = (const float*)d_in[5];
  const float* Wv = (const float*)d_in[6];
  const float* Wo = (const float*)d_in[7];
  float* out = (float*)d_out;

  char* base = (char*)d_ws;
  const size_t MB = 1u << 20;
  __hip_bfloat16* wtq = (__hip_bfloat16*)(base);
  __hip_bfloat16* wtk = (__hip_bfloat16*)(base + 512 * 1024);
  __hip_bfloat16* wtv = (__hip_bfloat16*)(base + 1 * MB);
  __hip_bfloat16* wto = (__hip_bfloat16*)(base + 1 * MB + 512 * 1024);
  __hip_bfloat16* qp = (__hip_bfloat16*)(base + 2 * MB);    // 8 MB each
  __hip_bfloat16* kp = (__hip_bfloat16*)(base + 10 * MB);
  __hip_bfloat16* vp = (__hip_bfloat16*)(base + 18 * MB);
  __hip_bfloat16* ao = (__hip_bfloat16*)(base + 26 * MB);
  unsigned long long* mb = (unsigned long long*)(base + 34 * MB);  // 33.6 MB

  mask_pack<<<dim3(2048), 256, 0, stream>>>(mask, mb);
  wconv<<<dim3(8, 8, 4), 256, 0, stream>>>(Wq, Wk, Wv, Wo, wtq, wtk, wtv, wto);
  gemm_qkv<<<dim3(128, 8, 3), 256, 0, stream>>>(
      q_in, k_in, v_in, wtq, wtk, wtv, qp, kp, vp);
  flash_attn<<<dim3(NS / 128, NH, NB), 256, 0, stream>>>(qp, kp, vp, mb, ao);
  gemm_out<<<dim3(128, 8), 256, 0, stream>>>(ao, wto, out);
}

// Round 4
// 1608.896 us; speedup vs baseline: 1.1790x; 1.0890x over previous
//
#include <hip/hip_runtime.h>
#include <hip/hip_bf16.h>

#define NB 2
#define NS 4096
#define NE 512
#define NH 8
#define ND 64
#define NHD 512

typedef __attribute__((ext_vector_type(8))) short short8;
typedef __attribute__((ext_vector_type(4))) float floatx4;
typedef __attribute__((ext_vector_type(16))) float f32x16;

#define MFMA16(a, b, c) __builtin_amdgcn_mfma_f32_16x16x32_bf16((a), (b), (c), 0, 0, 0)
#define MFMA32(a, b, c) __builtin_amdgcn_mfma_f32_32x32x16_bf16((a), (b), (c), 0, 0, 0)

union Cvt8 { uint4 u; short8 s; };
static __device__ __forceinline__ short8 ld8(const __hip_bfloat16* p) {
  Cvt8 c; c.u = *(const uint4*)p; return c.s;
}
union BH { __hip_bfloat16 h; short s; };
static __device__ __forceinline__ short f2bs(float x) {
  BH u; u.h = __float2bfloat16(x); return u.s;
}
// pack two f32 -> one u32 of 2x bf16 (lo = a, hi = b); RNE
static __device__ __forceinline__ unsigned pk2(float a, float b) {
  unsigned d;
  asm("v_cvt_pk_bf16_f32 %0, %1, %2" : "=v"(d) : "v"(a), "v"(b));
  return d;
}
// raw 2^x (v_exp_f32 computes exp2); scores are kept in log2 domain
static __device__ __forceinline__ float fexp2(float x) {
  float r;
  asm("v_exp_f32 %0, %1" : "=v"(r) : "v"(x));
  return r;
}

// ---------------------------------------------------------------------------
// Kernel 1: convert f32 -> bf16 and transpose 512x512 weights
// ---------------------------------------------------------------------------
__global__ __launch_bounds__(256) void wconv(
    const float* w0, const float* w1, const float* w2, const float* w3,
    __hip_bfloat16* t0, __hip_bfloat16* t1,
    __hip_bfloat16* t2, __hip_bfloat16* t3) {
  __shared__ __hip_bfloat16 tile[64][72];
  const float* src;
  __hip_bfloat16* dst;
  switch (blockIdx.z) {
    case 0: src = w0; dst = t0; break;
    case 1: src = w1; dst = t1; break;
    case 2: src = w2; dst = t2; break;
    default: src = w3; dst = t3; break;
  }
  const int tx = threadIdx.x & 63, ty = threadIdx.x >> 6;
  const int n0 = blockIdx.x * 64, k0 = blockIdx.y * 64;
  for (int r = ty; r < 64; r += 4)
    tile[r][tx] = __float2bfloat16(src[(long)(k0 + r) * 512 + n0 + tx]);
  __syncthreads();
  for (int r = ty; r < 64; r += 4)
    dst[(long)(n0 + r) * 512 + k0 + tx] = tile[tx][r];
}

// ---------------------------------------------------------------------------
// Kernel 2: QKV projection GEMM; Q output pre-scaled by 0.125*log2(e) so the
// flash softmax runs in the log2 domain (v_exp_f32 is 2^x; saves the mul).
// ---------------------------------------------------------------------------
__global__ __launch_bounds__(256) void gemm_qkv(
    const float* A0, const float* A1, const float* A2,
    const __hip_bfloat16* W0, const __hip_bfloat16* W1, const __hip_bfloat16* W2,
    __hip_bfloat16* O0, __hip_bfloat16* O1, __hip_bfloat16* O2) {
  const float* A;
  const __hip_bfloat16* Wt;
  __hip_bfloat16* O;
  switch (blockIdx.z) {
    case 0: A = A0; Wt = W0; O = O0; break;
    case 1: A = A1; Wt = W1; O = O1; break;
    default: A = A2; Wt = W2; O = O2; break;
  }
  const int lane = threadIdx.x & 63;
  const int w = threadIdx.x >> 6;
  const int c = lane & 15, g = lane >> 4;
  const int m0 = blockIdx.x * 64 + w * 16;
  const int n0 = blockIdx.y * 64;

  floatx4 acc[4] = {};
  const float* ap = A + (long)(m0 + c) * 512 + g * 8;
  const __hip_bfloat16* wp = Wt + (long)(n0 + c) * 512 + g * 8;
  for (int ks = 0; ks < 512; ks += 32) {
    const float4 f0 = *(const float4*)(ap + ks);
    const float4 f1 = *(const float4*)(ap + ks + 4);
    short8 a;
    a[0] = f2bs(f0.x); a[1] = f2bs(f0.y); a[2] = f2bs(f0.z); a[3] = f2bs(f0.w);
    a[4] = f2bs(f1.x); a[5] = f2bs(f1.y); a[6] = f2bs(f1.z); a[7] = f2bs(f1.w);
#pragma unroll
    for (int t = 0; t < 4; ++t) {
      short8 b = ld8(wp + t * 16 * 512 + ks);
      acc[t] = MFMA16(a, b, acc[t]);
    }
  }
  // 1/sqrt(64) * log2(e): scores land in log2 domain for flash
  const float sc = (blockIdx.z == 0) ? 0.125f * 1.44269504f : 1.0f;
#pragma unroll
  for (int t = 0; t < 4; ++t) {
#pragma unroll
    for (int r = 0; r < 4; ++r) {
      const int m = m0 + g * 4 + r;
      const int n = n0 + t * 16 + c;
      const int bb = m >> 12, s = m & 4095, h = n >> 6, d = n & 63;
      O[(((long)bb * NH + h) * NS + s) * ND + d] = __float2bfloat16(acc[t][r] * sc);
    }
  }
}

// ---------------------------------------------------------------------------
// Kernel 3: fused flash attention, swapped-QK^T 32x32 structure.
// grid (S/128, H, B); block 256 = 4 waves; each wave owns 32 q-rows.
// mfma(K,Q) -> lane (ql,hl) holds S[k=(r&3)+8*(r>>2)+4*hl (+32 for s1)][q=ql].
// Mask is read DIRECTLY as int32 (8x dwordx4 per lane per tile; k-labels come
// in contiguous 4-int runs) — issued before the barrier so latency hides
// under the barrier + QK^T MFMAs.  Softmax in log2 domain, fully in-register.
// ---------------------------------------------------------------------------
#define VPAD 72
__device__ __forceinline__ int vswz(int row) { return ((row >> 3) & 7) * 8; }

__global__ __launch_bounds__(256) void flash_attn(
    const __hip_bfloat16* Q, const __hip_bfloat16* K, const __hip_bfloat16* V,
    const int* __restrict__ mask, __hip_bfloat16* AO) {
  __shared__ __hip_bfloat16 Ks[64 * VPAD];
  __shared__ __hip_bfloat16 Vt[64 * VPAD];

  const int tid = threadIdx.x;
  const int lane = tid & 63, w = tid >> 6;
  const int ql = lane & 31, hl = lane >> 5;
  const int bz = blockIdx.z, hy = blockIdx.y;
  const int q0 = blockIdx.x * 128 + w * 32;
  const long headbase = ((long)bz * NH + hy) * NS;

  // Q fragments (B-operand): lane holds Q[q0+ql][ds*16 + hl*8 + j]
  short8 qf[4];
#pragma unroll
  for (int ds = 0; ds < 4; ++ds)
    qf[ds] = ld8(Q + (headbase + q0 + ql) * ND + ds * 16 + hl * 8);

  f32x16 oacc0 = {}, oacc1 = {};
  float m_i = -1e30f, l_i = 0.f;
  const int* mrow = mask + (headbase + q0 + ql) * (long)NS;

  for (int kt = 0; kt < 64; ++kt) {
    const int k0 = kt * 64;

    // ---- mask loads first (oldest in vmcnt queue; done by consume time) ----
    int4 mk0, mk1, mk2, mk3, mk4, mk5, mk6, mk7;
    {
      const int* mp = mrow + k0 + 4 * hl;
      mk0 = *(const int4*)(mp + 0);
      mk1 = *(const int4*)(mp + 8);
      mk2 = *(const int4*)(mp + 16);
      mk3 = *(const int4*)(mp + 24);
      mk4 = *(const int4*)(mp + 32);
      mk5 = *(const int4*)(mp + 40);
      mk6 = *(const int4*)(mp + 48);
      mk7 = *(const int4*)(mp + 56);
    }

#pragma unroll
    for (int it = 0; it < 2; ++it) {
      const int chunk = tid + it * 256;
      const int kc = chunk >> 3;
      const int dd = (chunk & 7) * 8;
      const long gbase = (headbase + k0 + kc) * ND + dd;
      *(uint4*)&Ks[kc * VPAD + dd] = *(const uint4*)(K + gbase);
      uint4 vv = *(const uint4*)(V + gbase);
      const __hip_bfloat16* ve = (const __hip_bfloat16*)&vv;
#pragma unroll
      for (int j = 0; j < 8; ++j) {
        const int row = dd + j;
        Vt[row * VPAD + (kc ^ vswz(row))] = ve[j];
      }
    }
    __syncthreads();

    // ---- S = K Q^T (swapped), log2 domain ----
    f32x16 s0 = {}, s1 = {};
#pragma unroll
    for (int ds = 0; ds < 4; ++ds) {
      short8 a0 = ld8(&Ks[ql * VPAD + ds * 16 + hl * 8]);
      s0 = MFMA32(a0, qf[ds], s0);
      short8 a1 = ld8(&Ks[(32 + ql) * VPAD + ds * 16 + hl * 8]);
      s1 = MFMA32(a1, qf[ds], s1);
    }

    // ---- mask (int4 runs; reg index of run rr covers r=4rr..4rr+3) ----
#pragma unroll
    for (int rr = 0; rr < 4; ++rr) {
      int4 a, b;
      switch (rr) {
        case 0: a = mk0; b = mk4; break;
        case 1: a = mk1; b = mk5; break;
        case 2: a = mk2; b = mk6; break;
        default: a = mk3; b = mk7; break;
      }
      if (a.x != 0) s0[4 * rr + 0] = -1e10f;
      if (a.y != 0) s0[4 * rr + 1] = -1e10f;
      if (a.z != 0) s0[4 * rr + 2] = -1e10f;
      if (a.w != 0) s0[4 * rr + 3] = -1e10f;
      if (b.x != 0) s1[4 * rr + 0] = -1e10f;
      if (b.y != 0) s1[4 * rr + 1] = -1e10f;
      if (b.z != 0) s1[4 * rr + 2] = -1e10f;
      if (b.w != 0) s1[4 * rr + 3] = -1e10f;
    }

    // ---- in-lane row max + cross-half combine ----
    float mt = -1e30f;
#pragma unroll
    for (int r = 0; r < 16; ++r)
      mt = fmaxf(mt, fmaxf(s0[r], s1[r]));
    mt = fmaxf(mt, __shfl_xor(mt, 32));

    // ---- defer-rescale (THR=8 in log2 domain; P bounded by 2^8) ----
    if (__ballot(mt > m_i + 8.0f) != 0ull) {
      const float mn = fmaxf(m_i, mt);
      const float al = fexp2(m_i - mn);
      m_i = mn;
      l_i *= al;
#pragma unroll
      for (int r = 0; r < 16; ++r) {
        const float ab = __shfl(al, (r & 3) + 8 * (r >> 2) + 4 * hl);
        oacc0[r] *= ab;
        oacc1[r] *= ab;
      }
    }

    // ---- exp2 + in-lane sum ----
    float ss = 0.f;
#pragma unroll
    for (int r = 0; r < 16; ++r) {
      const float p0 = fexp2(s0[r] - m_i);
      const float p1 = fexp2(s1[r] - m_i);
      s0[r] = p0; s1[r] = p1;
      ss += p0 + p1;
    }
    ss += __shfl_xor(ss, 32);
    l_i += ss;

    // ---- P->bf16 A-frags (2 shfl_xor(32) + selects per 16-group) ----
#pragma unroll
    for (int ks = 0; ks < 4; ++ks) {
      float pp[8];
#pragma unroll
      for (int j = 0; j < 8; ++j)
        pp[j] = (ks < 2) ? ((ks & 1) ? s0[8 + j] : s0[j])
                         : ((ks & 1) ? s1[8 + j] : s1[j]);
      const unsigned pk01 = pk2(pp[0], pp[1]);  // hl0:(0,1)  hl1:(4,5)
      const unsigned pk23 = pk2(pp[2], pp[3]);  // hl0:(2,3)  hl1:(6,7)
      const unsigned pk45 = pk2(pp[4], pp[5]);  // hl0:(8,9)  hl1:(12,13)
      const unsigned pk67 = pk2(pp[6], pp[7]);  // hl0:(10,11) hl1:(14,15)
      const unsigned send1 = hl ? pk01 : pk45;
      const unsigned send2 = hl ? pk23 : pk67;
      const unsigned recv1 = __shfl_xor(send1, 32);  // hl0:(4,5)  hl1:(8,9)
      const unsigned recv2 = __shfl_xor(send2, 32);  // hl0:(6,7)  hl1:(10,11)
      Cvt8 pc;
      pc.u = make_uint4(hl ? recv1 : pk01,   // w0: hl0 (0,1)  hl1 (8,9)
                        hl ? recv2 : pk23,   // w1: hl0 (2,3)  hl1 (10,11)
                        hl ? pk45 : recv1,   // w2: hl0 (4,5)  hl1 (12,13)
                        hl ? pk67 : recv2);  // w3: hl0 (6,7)  hl1 (14,15)
      const int cb = ks * 16 + hl * 8;
      const short8 v0 = ld8(&Vt[ql * VPAD + (cb ^ vswz(ql))]);
      oacc0 = MFMA32(pc.s, v0, oacc0);
      const short8 v1 = ld8(&Vt[(32 + ql) * VPAD + (cb ^ vswz(32 + ql))]);
      oacc1 = MFMA32(pc.s, v1, oacc1);
    }
    __syncthreads();
  }

  // ---- epilogue: fetch l for own output rows, normalize, store ----
#pragma unroll
  for (int r = 0; r < 16; ++r) {
    const int cr = (r & 3) + 8 * (r >> 2) + 4 * hl;
    const float lb = __shfl(l_i, cr);  // l_i for q=cr lives at lane cr
    const float inv = 1.0f / lb;
    const long obase = ((long)bz * NS + q0 + cr) * NHD + hy * 64;
    AO[obase + ql] = __float2bfloat16(oacc0[r] * inv);
    AO[obase + 32 + ql] = __float2bfloat16(oacc1[r] * inv);
  }
}

// ---------------------------------------------------------------------------
// Kernel 4: output projection.  A (bf16, M x 512) @ Wo^T -> out (f32).
// ---------------------------------------------------------------------------
__global__ __launch_bounds__(256) void gemm_out(
    const __hip_bfloat16* A, const __hip_bfloat16* Wt, float* O) {
  const int lane = threadIdx.x & 63;
  const int w = threadIdx.x >> 6;
  const int c = lane & 15, g = lane >> 4;
  const int m0 = blockIdx.x * 64 + w * 16;
  const int n0 = blockIdx.y * 64;

  floatx4 acc[4] = {};
  const __hip_bfloat16* ap = A + (long)(m0 + c) * 512 + g * 8;
  const __hip_bfloat16* wp = Wt + (long)(n0 + c) * 512 + g * 8;
  for (int ks = 0; ks < 512; ks += 32) {
    short8 a = ld8(ap + ks);
#pragma unroll
    for (int t = 0; t < 4; ++t) {
      short8 b = ld8(wp + t * 16 * 512 + ks);
      acc[t] = MFMA16(a, b, acc[t]);
    }
  }
#pragma unroll
  for (int t = 0; t < 4; ++t)
#pragma unroll
    for (int r = 0; r < 4; ++r)
      O[(long)(m0 + g * 4 + r) * 512 + n0 + t * 16 + c] = acc[t][r];
}

// ---------------------------------------------------------------------------
extern "C" void kernel_launch(void* const* d_in, const int* in_sizes, int n_in,
                              void* d_out, int out_size, void* d_ws, size_t ws_size,
                              hipStream_t stream) {
  const float* q_in = (const float*)d_in[0];
  const float* k_in = (const float*)d_in[1];
  const float* v_in = (const float*)d_in[2];
  const int* mask = (const int*)d_in[3];
  const float* Wq = (const float*)d_in[4];
  const float* Wk = (const float*)d_in[5];
  const float* Wv = (const float*)d_in[6];
  const float* Wo = (const float*)d_in[7];
  float* out = (float*)d_out;

  char* base = (char*)d_ws;
  const size_t MB = 1u << 20;
  __hip_bfloat16* wtq = (__hip_bfloat16*)(base);
  __hip_bfloat16* wtk = (__hip_bfloat16*)(base + 512 * 1024);
  __hip_bfloat16* wtv = (__hip_bfloat16*)(base + 1 * MB);
  __hip_bfloat16* wto = (__hip_bfloat16*)(base + 1 * MB + 512 * 1024);
  __hip_bfloat16* qp = (__hip_bfloat16*)(base + 2 * MB);    // 8 MB each
  __hip_bfloat16* kp = (__hip_bfloat16*)(base + 10 * MB);
  __hip_bfloat16* vp = (__hip_bfloat16*)(base + 18 * MB);
  __hip_bfloat16* ao = (__hip_bfloat16*)(base + 26 * MB);

  wconv<<<dim3(8, 8, 4), 256, 0, stream>>>(Wq, Wk, Wv, Wo, wtq, wtk, wtv, wto);
  gemm_qkv<<<dim3(128, 8, 3), 256, 0, stream>>>(
      q_in, k_in, v_in, wtq, wtk, wtv, qp, kp, vp);
  flash_attn<<<dim3(NS / 128, NH, NB), 256, 0, stream>>>(qp, kp, vp, mask, ao);
  gemm_out<<<dim3(128, 8), 256, 0, stream>>>(ao, wto, out);
}